// Round 11
// baseline (934.421 us; speedup 1.0000x reference)
//
#include <hip/hip_runtime.h>

typedef float v2f __attribute__((ext_vector_type(2)));

#define T_LEN 2048
#define NH    10
#define OUT_T 1439
#define TFIRST 608      // out[k] = fc(h1(TFIRST+k)), k in [0,1439)
#define NSEQ  4096
#define CH    16        // steps per hand-off chunk
#define NCH   (T_LEN / CH)      // 128

#define KSIG (-1.4426950408889634f)   // -log2(e)      (sigmoid arg scale)
#define KTAN (-2.8853900817779268f)   // -2*log2(e)    (tanh arg scale)

static __device__ __forceinline__ v2f fma2(v2f a, v2f b, v2f c) {
  return __builtin_elementwise_fma(a, b, c);
}
static __device__ __forceinline__ v2f splat2(float v) { v2f r; r.x = v; r.y = v; return r; }
static __device__ __forceinline__ v2f mulsp(v2f a, float s) { v2f r; r.x = a.x*s; r.y = a.y*s; return r; }
static __device__ __forceinline__ float rcp1p(float e) {   // rcp(1+e)
  return __builtin_amdgcn_rcpf(1.0f + e);
}

// DPP row_ror:N within rows of 16 (verified R1-R9): dest[i] = src[(i-N)&15]
#define ROR_F(v, N) __uint_as_float(__builtin_amdgcn_update_dpp( \
    0, (int)__float_as_uint(v), 0x120 + (N), 0xF, 0xF, true))

// 2-WAVE PIPELINE + DPP RECURRENCE RING (R10 = R8 structure, DS-free self-bcast):
//   Wave A: layer-0. Recurrent dot via 16-term DPP rotation ring on the h0
//     REGISTER (pre-rotated weights w[(u-k)&15], zero-padded — R1-verified).
//     Writes h0(t) to h0buf for B only (fire-and-forget). DS: 1 write/step.
//   Wave B: layer-1, one chunk behind. Input dot from h0buf vector reads
//     (old data, no write dependency); recurrent dot via its own DPP ring on
//     h1 register. fc1 is FOLDED into the ring's pad-lane weights (lanes
//     u=10..15 carry fc1 rows in the "g" slot, which gets the tanh path);
//     fc2 = 1 mul + 4 DPP-ror reduce + guarded store, inline, on t>TFIRST.
//     DS: 3 reads/step. No h1buf, no separate fc pass.
//   Round r: A chunk r -> h0buf[r&1]; B chunk r-1 from h0buf[(r-1)&1].
//   One __syncthreads per round (129 total).
// Lane layout (verified R0-R9): 4 seqs/wave, 16 lanes/seq, lane u<10 owns
// unit u, gate rows packed (i,f)/(g,o) in v2f, weights pre-scaled KSIG/KTAN,
// cell state kept KTAN-scaled.
__global__ void __launch_bounds__(128, 2)
lstm_fused(const float* __restrict__ x,
           const float* __restrict__ w_ih0, const float* __restrict__ w_hh0,
           const float* __restrict__ b_ih0, const float* __restrict__ b_hh0,
           const float* __restrict__ w_ih1, const float* __restrict__ w_hh1,
           const float* __restrict__ b_ih1, const float* __restrict__ b_hh1,
           const float* __restrict__ fc1_w, const float* __restrict__ fc1_b,
           const float* __restrict__ fc2_w, const float* __restrict__ fc2_b,
           float* __restrict__ out)
{
  __shared__ __align__(16) float h0buf[2][CH][64];

  const int tid  = threadIdx.x;       // 0..127
  const int wid  = tid >> 6;          // 0=A(L0) 1=B(L1+FC)
  const int lane = tid & 63;
  const int grp  = lane >> 4;         // sequence within wave (0..3)
  const int u    = lane & 15;         // unit slot within group
  const int seq  = (int)blockIdx.x * 4 + grp;

  // Ring weights (k: multiplies h[(u-k)&15]):
  //   A: wRif/wRgo = w_hh0 ring ; B: w_hh1 ring (+fc1 fold on pad .x slot)
  // Input weights (B only): wIF/wGO = w_ih1 rows (j-indexed, consumed from LDS)
  v2f wRif[16], wRgo[16], wIF[NH], wGO[NH];
  v2f wx_if, wx_go, bb_if, bb_go;
  wx_if = wx_go = bb_if = bb_go = splat2(0.f);
#pragma unroll
  for (int k = 0; k < 16; ++k) { wRif[k] = splat2(0.f); wRgo[k] = splat2(0.f); }
#pragma unroll
  for (int j = 0; j < NH; ++j) { wIF[j] = splat2(0.f); wGO[j] = splat2(0.f); }
  float fc2s = 0.f;
  const float fc2bl = fc2_b[0];

  if (wid == 0) {
    if (u < NH) {
      const int ri = 0*NH+u, rf = 1*NH+u, rg = 2*NH+u, ro = 3*NH+u;
      wx_if.x = KSIG * w_ih0[ri];            wx_if.y = KSIG * w_ih0[rf];
      wx_go.x = KTAN * w_ih0[rg];            wx_go.y = KSIG * w_ih0[ro];
      bb_if.x = KSIG * (b_ih0[ri] + b_hh0[ri]); bb_if.y = KSIG * (b_ih0[rf] + b_hh0[rf]);
      bb_go.x = KTAN * (b_ih0[rg] + b_hh0[rg]); bb_go.y = KSIG * (b_ih0[ro] + b_hh0[ro]);
#pragma unroll
      for (int k = 0; k < 16; ++k) {
        const int j = (u - k) & 15;
        if (j < NH) {
          wRif[k].x = KSIG * w_hh0[ri*NH+j]; wRif[k].y = KSIG * w_hh0[rf*NH+j];
          wRgo[k].x = KTAN * w_hh0[rg*NH+j]; wRgo[k].y = KSIG * w_hh0[ro*NH+j];
        }
      }
    }
  } else {
    if (u < NH) {
      const int ri = 0*NH+u, rf = 1*NH+u, rg = 2*NH+u, ro = 3*NH+u;
      bb_if.x = KSIG * (b_ih1[ri] + b_hh1[ri]); bb_if.y = KSIG * (b_ih1[rf] + b_hh1[rf]);
      bb_go.x = KTAN * (b_ih1[rg] + b_hh1[rg]); bb_go.y = KSIG * (b_ih1[ro] + b_hh1[ro]);
#pragma unroll
      for (int j = 0; j < NH; ++j) {
        wIF[j].x = KSIG * w_ih1[ri*NH+j]; wIF[j].y = KSIG * w_ih1[rf*NH+j];
        wGO[j].x = KTAN * w_ih1[rg*NH+j]; wGO[j].y = KSIG * w_ih1[ro*NH+j];
      }
#pragma unroll
      for (int k = 0; k < 16; ++k) {
        const int j = (u - k) & 15;
        if (j < NH) {
          wRif[k].x = KSIG * w_hh1[ri*NH+j]; wRif[k].y = KSIG * w_hh1[rf*NH+j];
          wRgo[k].x = KTAN * w_hh1[rg*NH+j]; wRgo[k].y = KSIG * w_hh1[ro*NH+j];
        }
      }
    } else {
      const int p = u - NH;                 // 0..5: fc1 row, folded into ring "g"
      bb_go.x = KTAN * fc1_b[p];
      fc2s = fc2_w[p] / KTAN;               // tgp * fc2s = fc2_w * tanh(fc1.)
#pragma unroll
      for (int k = 0; k < 16; ++k) {
        const int j = (u - k) & 15;
        if (j < NH) wRgo[k].x = KTAN * fc1_w[p*NH + j];
      }
    }
  }

  const float* xp   = x + (size_t)seq * T_LEN;
  float*       outp = out + (size_t)seq * OUT_T;

  float c = 0.f;                            // KTAN-scaled cell state
  float h = 0.f;                            // this lane's own h (unit u)

  // Ring macro: term k into accumulator pair (alternating parity)
#define RK(K, AIF, AGO) { const float hk = ROR_F(h, K); const v2f sp = splat2(hk); \
    AIF = fma2(wRif[K], sp, AIF); AGO = fma2(wRgo[K], sp, AGO); }

  // ---- A: one L0 step; h0 -> LDS (for B) ; ring keeps self-recurrence ----
  auto l0_step = [&](float xv, float* dst) {
    v2f aA = fma2(wx_if, splat2(xv), bb_if);
    v2f gA = fma2(wx_go, splat2(xv), bb_go);
    { const v2f sp = splat2(h); aA = fma2(wRif[0], sp, aA); gA = fma2(wRgo[0], sp, gA); }
    const float h1r = ROR_F(h, 1);
    v2f aB = mulsp(wRif[1], h1r);
    v2f gB = mulsp(wRgo[1], h1r);
    RK(2,aA,gA)  RK(3,aB,gB)  RK(4,aA,gA)  RK(5,aB,gB)
    RK(6,aA,gA)  RK(7,aB,gB)  RK(8,aA,gA)  RK(9,aB,gB)
    RK(10,aA,gA) RK(11,aB,gB) RK(12,aA,gA) RK(13,aB,gB)
    RK(14,aA,gA) RK(15,aB,gB)
    const v2f gif = aA + aB;
    const v2f ggo = gA + gB;
    const float si = rcp1p(__builtin_amdgcn_exp2f(gif.x));
    const float sf = rcp1p(__builtin_amdgcn_exp2f(gif.y));
    const float rg = rcp1p(__builtin_amdgcn_exp2f(ggo.x));
    const float so = rcp1p(__builtin_amdgcn_exp2f(ggo.y));
    const float tgp = __builtin_fmaf(rg, 2.f*KTAN, -KTAN);  // KTAN*tanh(g)
    c = __builtin_fmaf(sf, c, si * tgp);                    // c' = KTAN*c
    const float rc = rcp1p(__builtin_amdgcn_exp2f(c));
    const float tc = __builtin_fmaf(rc, 2.f, -1.f);         // tanh(c)
    h = so * tc;                                            // pad lanes: exactly 0
    *dst = h;                                               // off-chain (for B)
  };

  auto a_chunk = [&](int m) {
    float* hb = &h0buf[m & 1][0][0] + lane;
    const float4* xq = (const float4*)(xp + m * CH);
    float4 xw[CH / 4];
#pragma unroll
    for (int i = 0; i < CH / 4; ++i) xw[i] = xq[i];
#pragma unroll
    for (int s = 0; s < CH; ++s) l0_step(((const float*)xw)[s], hb + s * 64);
  };

  // ---- B: one L1 step; input from LDS, self-recurrence ring, inline fc ----
  auto l1_step = [&](const float* hp, float* optr, bool do_out) {
    const float4 pa = *(const float4*)(hp);
    const float4 pb = *(const float4*)(hp + 4);
    const float2 pc = *(const float2*)(hp + 8);
    v2f cA = fma2(wIF[0], splat2(pa.x), bb_if);
    v2f hA = fma2(wGO[0], splat2(pa.x), bb_go);
    v2f cB = mulsp(wIF[1], pa.y);
    v2f hB = mulsp(wGO[1], pa.y);
#define L1I(j, hv, AC, GC) { const v2f sp = splat2(hv); \
    AC = fma2(wIF[j], sp, AC); GC = fma2(wGO[j], sp, GC); }
    L1I(2,pa.z,cA,hA) L1I(3,pa.w,cB,hB) L1I(4,pb.x,cA,hA) L1I(5,pb.y,cB,hB)
    L1I(6,pb.z,cA,hA) L1I(7,pb.w,cB,hB) L1I(8,pc.x,cA,hA) L1I(9,pc.y,cB,hB)
#undef L1I
    { const v2f sp = splat2(h); cA = fma2(wRif[0], sp, cA); hA = fma2(wRgo[0], sp, hA); }
    RK(1,cB,hB)  RK(2,cA,hA)  RK(3,cB,hB)  RK(4,cA,hA)
    RK(5,cB,hB)  RK(6,cA,hA)  RK(7,cB,hB)  RK(8,cA,hA)
    RK(9,cB,hB)  RK(10,cA,hA) RK(11,cB,hB) RK(12,cA,hA)
    RK(13,cB,hB) RK(14,cA,hA) RK(15,cB,hB)
    const v2f gif = cA + cB;
    const v2f ggo = hA + hB;
    const float si = rcp1p(__builtin_amdgcn_exp2f(gif.x));
    const float sf = rcp1p(__builtin_amdgcn_exp2f(gif.y));
    const float rg = rcp1p(__builtin_amdgcn_exp2f(ggo.x));
    const float so = rcp1p(__builtin_amdgcn_exp2f(ggo.y));
    const float tgp = __builtin_fmaf(rg, 2.f*KTAN, -KTAN);  // pads: KTAN*tanh(fc1(h1(t-1)))
    c = __builtin_fmaf(sf, c, si * tgp);
    const float rc = rcp1p(__builtin_amdgcn_exp2f(c));
    const float tc = __builtin_fmaf(rc, 2.f, -1.f);
    h = so * tc;                                            // pads: bounded, ring-weight 0
    if (do_out) {                                           // fc2 for timestep t-1
      float y = tgp * fc2s;                                 // nonzero only on pads
      y += ROR_F(y, 8);
      y += ROR_F(y, 4);
      y += ROR_F(y, 2);
      y += ROR_F(y, 1);                                     // whole 16-group holds sum
      if (u == 0) *optr = y + fc2bl;
    }
  };

  auto b_chunk = [&](int m) {
    const float* hbi = &h0buf[m & 1][0][grp * 16];
    const int tbase = m * CH;
    float* oq = outp + (tbase - 1 - TFIRST);
#pragma unroll
    for (int s = 0; s < CH; ++s)
      l1_step(hbi + s * 64, oq + s, tbase + s > TFIRST);
  };
#undef RK

  // ---- pipeline: round r = {A: L0 chunk r ; B: L1+fc chunk r-1} ----
#pragma unroll 1
  for (int r = 0; r < NCH + 1; ++r) {
    if (wid == 0) {
      if (r < NCH) a_chunk(r);
    } else {
      if (r >= 1) b_chunk(r - 1);
    }
    __syncthreads();
  }
}

extern "C" void kernel_launch(void* const* d_in, const int* in_sizes, int n_in,
                              void* d_out, int out_size, void* d_ws, size_t ws_size,
                              hipStream_t stream) {
  const float* x     = (const float*)d_in[0];
  const float* w_ih0 = (const float*)d_in[1];
  const float* w_hh0 = (const float*)d_in[2];
  const float* b_ih0 = (const float*)d_in[3];
  const float* b_hh0 = (const float*)d_in[4];
  const float* w_ih1 = (const float*)d_in[5];
  const float* w_hh1 = (const float*)d_in[6];
  const float* b_ih1 = (const float*)d_in[7];
  const float* b_hh1 = (const float*)d_in[8];
  const float* fc1_w = (const float*)d_in[9];
  const float* fc1_b = (const float*)d_in[10];
  const float* fc2_w = (const float*)d_in[11];
  const float* fc2_b = (const float*)d_in[12];
  float* out = (float*)d_out;

  lstm_fused<<<dim3(NSEQ / 4), dim3(128), 0, stream>>>(
      x, w_ih0, w_hh0, b_ih0, b_hh0, w_ih1, w_hh1, b_ih1, b_hh1,
      fc1_w, fc1_b, fc2_w, fc2_b, out);
}

// Round 12
// 687.868 us; speedup vs baseline: 1.3584x; 1.3584x over previous
//
#include <hip/hip_runtime.h>

typedef float v2f __attribute__((ext_vector_type(2)));

#define T_LEN 2048
#define NH    10
#define OUT_T 1439
#define TFIRST 608      // first output timestep: out[k] = fc(h1(TFIRST+k))
#define NSEQ  4096
#define CH    16        // steps per hand-off chunk
#define NCH   (T_LEN / CH)      // 128
#define MFIRST (TFIRST / CH)    // 38 (exact)

#define KSIG (-1.4426950408889634f)   // -log2(e)      (sigmoid arg scale)
#define KTAN (-2.8853900817779268f)   // -2*log2(e)    (tanh arg scale)

static __device__ __forceinline__ v2f fma2(v2f a, v2f b, v2f c) {
  return __builtin_elementwise_fma(a, b, c);
}
static __device__ __forceinline__ v2f splat2(float v) { v2f r; r.x = v; r.y = v; return r; }
static __device__ __forceinline__ v2f mulsp(v2f a, float s) { v2f r; r.x = a.x*s; r.y = a.y*s; return r; }
static __device__ __forceinline__ float rcp1p(float e) {   // rcp(1+e)
  return __builtin_amdgcn_rcpf(1.0f + e);
}

// DPP row_ror:N within rows of 16 (verified R1-R10): dest[i] = src[(i-N)&15]
#define ROR_F(v, N) __uint_as_float(__builtin_amdgcn_update_dpp( \
    0, (int)__float_as_uint(v), 0x120 + (N), 0xF, 0xF, true))

// 2-WAVE BALANCED PIPELINE (R8 structure, verified 724us) + R11 TRANS DIET:
//   Wave A: layer-0 recurrence -> h0buf + fc head (h1buf, two chunks back).
//   Wave B: layer-1 recurrence -> h1buf, one chunk behind A.
//   Self-broadcast: LDS write + b128/b64 readback (in-order same-wave DS) —
//   R9 (swizzle) and R10 (DPP ring) both proved costlier in issue.
//   R11: 8 transcendentals per cell instead of 10 via fused forms
//     sig(i)*tanh(g) = (1-eg) / ((1+ei)(1+eg))      [one rcp]
//     sig(o)*tanh(c) = (1-ec) / ((1+eo)(1+ec))      [one rcp]
//   with exp2-arg clamp +-64 on the cell state (tanh(+-22) saturates exactly;
//   prevents Inf*0=NaN for pathological deep-negative c).
//   Round r: A does L0 chunk r + fc chunk r-2; B does L1 chunk r-1.
//   Parity: A writes h0[r&1]; B reads h0[(r-1)&1], writes h1[(r-1)&1];
//   A's fc reads h1[(r-2)&1] = h1[r&1]. One __syncthreads per round.
__global__ void __launch_bounds__(128, 2)
lstm_fused(const float* __restrict__ x,
           const float* __restrict__ w_ih0, const float* __restrict__ w_hh0,
           const float* __restrict__ b_ih0, const float* __restrict__ b_hh0,
           const float* __restrict__ w_ih1, const float* __restrict__ w_hh1,
           const float* __restrict__ b_ih1, const float* __restrict__ b_hh1,
           const float* __restrict__ fc1_w, const float* __restrict__ fc1_b,
           const float* __restrict__ fc2_w, const float* __restrict__ fc2_b,
           float* __restrict__ out)
{
  __shared__ __align__(16) float h0buf[2][CH][64];
  __shared__ __align__(16) float h1buf[2][CH][64];

  const int tid  = threadIdx.x;       // 0..127
  const int wid  = tid >> 6;          // 0=A(L0+FC) 1=B(L1)
  const int lane = tid & 63;
  const int grp  = lane >> 4;         // sequence within wave (0..3)
  const int u    = lane & 15;         // unit slot within group
  const int seq  = (int)blockIdx.x * 4 + grp;

  v2f wIF[NH], wGO[NH], vIF[NH], vGO[NH];
  v2f wx_if, wx_go, bb_if, bb_go;
  wx_if = wx_go = bb_if = bb_go = splat2(0.f);
#pragma unroll
  for (int j = 0; j < NH; ++j) {
    wIF[j] = splat2(0.f); wGO[j] = splat2(0.f);
    vIF[j] = splat2(0.f); vGO[j] = splat2(0.f);
  }
  float fcw[NH];
#pragma unroll
  for (int j = 0; j < NH; ++j) fcw[j] = 0.f;
  float fcb = 0.f, fc2w2 = 0.f, fc2wn = 0.f;
  const float fc2bl = fc2_b[0];

  if (wid == 0) {
    if (u < NH) {
      const int ri = 0*NH+u, rf = 1*NH+u, rg = 2*NH+u, ro = 3*NH+u;
      wx_if.x = KSIG * w_ih0[ri];            wx_if.y = KSIG * w_ih0[rf];
      wx_go.x = KTAN * w_ih0[rg];            wx_go.y = KSIG * w_ih0[ro];
      bb_if.x = KSIG * (b_ih0[ri] + b_hh0[ri]); bb_if.y = KSIG * (b_ih0[rf] + b_hh0[rf]);
      bb_go.x = KTAN * (b_ih0[rg] + b_hh0[rg]); bb_go.y = KSIG * (b_ih0[ro] + b_hh0[ro]);
#pragma unroll
      for (int j = 0; j < NH; ++j) {
        wIF[j].x = KSIG * w_hh0[ri*NH+j]; wIF[j].y = KSIG * w_hh0[rf*NH+j];
        wGO[j].x = KTAN * w_hh0[rg*NH+j]; wGO[j].y = KSIG * w_hh0[ro*NH+j];
      }
    }
    if (u < 6) {                 // fc head: fc1 row scaled by KTAN; fc2 folded
      fcb = KTAN * fc1_b[u];
      const float w2 = fc2_w[u];
      fc2w2 = 2.f * w2; fc2wn = -w2;
#pragma unroll
      for (int j = 0; j < NH; ++j) fcw[j] = KTAN * fc1_w[u*NH + j];
    }
  } else {
    if (u < NH) {
      const int ri = 0*NH+u, rf = 1*NH+u, rg = 2*NH+u, ro = 3*NH+u;
      bb_if.x = KSIG * (b_ih1[ri] + b_hh1[ri]); bb_if.y = KSIG * (b_ih1[rf] + b_hh1[rf]);
      bb_go.x = KTAN * (b_ih1[rg] + b_hh1[rg]); bb_go.y = KSIG * (b_ih1[ro] + b_hh1[ro]);
#pragma unroll
      for (int j = 0; j < NH; ++j) {
        wIF[j].x = KSIG * w_ih1[ri*NH+j]; wIF[j].y = KSIG * w_ih1[rf*NH+j];
        wGO[j].x = KTAN * w_ih1[rg*NH+j]; wGO[j].y = KSIG * w_ih1[ro*NH+j];
        vIF[j].x = KSIG * w_hh1[ri*NH+j]; vIF[j].y = KSIG * w_hh1[rf*NH+j];
        vGO[j].x = KTAN * w_hh1[rg*NH+j]; vGO[j].y = KSIG * w_hh1[ro*NH+j];
      }
    }
  }

  const float* xp   = x + (size_t)seq * T_LEN;
  float*       outp = out + (size_t)seq * OUT_T;

  float c = 0.f;                                  // KTAN-scaled cell state
  float r0=0.f,r1=0.f,r2=0.f,r3=0.f,r4=0.f,r5=0.f,r6=0.f,r7=0.f,r8=0.f,r9=0.f;

  // ---- 8-trans activation tail: consumes (gif, ggo), updates c, returns h ----
  auto act_tail = [&](v2f gif, v2f ggo) -> float {
    const float ei = __builtin_amdgcn_exp2f(gif.x);
    const float ef = __builtin_amdgcn_exp2f(gif.y);
    const float eg = __builtin_amdgcn_exp2f(ggo.x);
    const float eo = __builtin_amdgcn_exp2f(ggo.y);
    const float sf = rcp1p(ef);                               // sigma(f)
    const float ai = 1.0f + ei;
    const float d1 = __builtin_fmaf(ai, eg, ai);              // (1+ei)(1+eg)
    const float r1_ = __builtin_amdgcn_rcpf(d1);
    const float num = __builtin_fmaf(-KTAN, eg, KTAN);        // KTAN*(1-eg)
    c = __builtin_fmaf(sf, c, num * r1_);                     // c' = KTAN*c_true
    const float cc = __builtin_fminf(__builtin_fmaxf(c, -64.f), 64.f);
    const float ec = __builtin_amdgcn_exp2f(cc);
    const float ao = 1.0f + eo;
    const float d2 = __builtin_fmaf(ao, ec, ao);              // (1+eo)(1+ec)
    const float r2_ = __builtin_amdgcn_rcpf(d2);
    return __builtin_fmaf(-ec, r2_, r2_);                     // sigma(o)*tanh(c)
  };

  // ---- A: produce h0 for steps m*CH .. m*CH+CH-1 into h0buf[m&1] ----
  auto a_chunk = [&](int m) {
    float* hb = &h0buf[m & 1][0][0];
    const float* hr = &h0buf[m & 1][0][grp * 16];
    const float4* xq = (const float4*)(xp + m * CH);
    float4 xw[CH / 4];
#pragma unroll
    for (int i = 0; i < CH / 4; ++i) xw[i] = xq[i];
#pragma unroll
    for (int s = 0; s < CH; ++s) {
      const float xv = ((const float*)xw)[s];
      v2f aA = fma2(wx_if, splat2(xv), bb_if);
      v2f gA = fma2(wx_go, splat2(xv), bb_go);
      v2f aB = mulsp(wIF[1], r1);
      v2f gB = mulsp(wGO[1], r1);
#define L0T(j, hv, AC, GC) { const v2f sp = splat2(hv); \
      AC = fma2(wIF[j], sp, AC); GC = fma2(wGO[j], sp, GC); }
      L0T(0,r0,aA,gA) L0T(2,r2,aA,gA) L0T(3,r3,aB,gB) L0T(4,r4,aA,gA)
      L0T(5,r5,aB,gB) L0T(6,r6,aA,gA) L0T(7,r7,aB,gB) L0T(8,r8,aA,gA)
      L0T(9,r9,aB,gB)
#undef L0T
      const float h0n = act_tail(aA + aB, gA + gB);
      hb[s*64 + lane] = h0n;
      const float4 va = *(const float4*)(hr + s*64);
      const float4 vb = *(const float4*)(hr + s*64 + 4);
      const float2 vc = *(const float2*)(hr + s*64 + 8);
      r0=va.x; r1=va.y; r2=va.z; r3=va.w;
      r4=vb.x; r5=vb.y; r6=vb.z; r7=vb.w;
      r8=vc.x; r9=vc.y;
    }
  };

  // ---- B: consume h0 chunk m, produce h1 chunk m into h1buf[m&1] ----
  auto b_chunk = [&](int m) {
    const float* hbi = &h0buf[m & 1][0][grp * 16];
    float* ob = &h1buf[m & 1][0][0];
    const float* orr = &h1buf[m & 1][0][grp * 16];
#pragma unroll
    for (int s = 0; s < CH; ++s) {
      const float4 pa = *(const float4*)(hbi + s*64);
      const float4 pb = *(const float4*)(hbi + s*64 + 4);
      const float2 pc = *(const float2*)(hbi + s*64 + 8);
      v2f cA = fma2(wIF[0], splat2(pa.x), bb_if);
      v2f hA = fma2(wGO[0], splat2(pa.x), bb_go);
      v2f cB = mulsp(wIF[1], pa.y);
      v2f hB = mulsp(wGO[1], pa.y);
#define L1I(j, hv, AC, GC) { const v2f sp = splat2(hv); \
      AC = fma2(wIF[j], sp, AC); GC = fma2(wGO[j], sp, GC); }
      L1I(2,pa.z,cA,hA) L1I(3,pa.w,cB,hB) L1I(4,pb.x,cA,hA) L1I(5,pb.y,cB,hB)
      L1I(6,pb.z,cA,hA) L1I(7,pb.w,cB,hB) L1I(8,pc.x,cA,hA) L1I(9,pc.y,cB,hB)
#undef L1I
      v2f cC = mulsp(vIF[0], r0);
      v2f hC = mulsp(vGO[0], r0);
      v2f cD = mulsp(vIF[1], r1);
      v2f hD = mulsp(vGO[1], r1);
#define L1R(j, hv, AC, GC) { const v2f sp = splat2(hv); \
      AC = fma2(vIF[j], sp, AC); GC = fma2(vGO[j], sp, GC); }
      L1R(2,r2,cC,hC) L1R(3,r3,cD,hD) L1R(4,r4,cC,hC) L1R(5,r5,cD,hD)
      L1R(6,r6,cC,hC) L1R(7,r7,cD,hD) L1R(8,r8,cC,hC) L1R(9,r9,cD,hD)
#undef L1R
      const float h1n = act_tail((cA + cB) + (cC + cD), (hA + hB) + (hC + hD));
      ob[s*64 + lane] = h1n;
      const float4 va = *(const float4*)(orr + s*64);
      const float4 vb = *(const float4*)(orr + s*64 + 4);
      const float2 vc = *(const float2*)(orr + s*64 + 8);
      r0=va.x; r1=va.y; r2=va.z; r3=va.w;
      r4=vb.x; r5=vb.y; r6=vb.z; r7=vb.w;
      r8=vc.x; r9=vc.y;
    }
  };

  // ---- A also runs the fc head on h1 chunk m (two rounds behind) ----
  auto fc_chunk = [&](int m) {
    const float* hb = &h1buf[m & 1][0][grp * 16];
    float* oq = outp + (m * CH - TFIRST);
#pragma unroll
    for (int s = 0; s < CH; ++s) {
      if (m * CH + s < TFIRST + OUT_T) {          // t <= 2046
        const float4 pa = *(const float4*)(hb + s*64);
        const float4 pb = *(const float4*)(hb + s*64 + 4);
        const float2 pc = *(const float2*)(hb + s*64 + 8);
        float acc = __builtin_fmaf(pa.x, fcw[0], fcb);        // KTAN-scaled
        acc = __builtin_fmaf(pa.y, fcw[1], acc);
        acc = __builtin_fmaf(pa.z, fcw[2], acc);
        acc = __builtin_fmaf(pa.w, fcw[3], acc);
        acc = __builtin_fmaf(pb.x, fcw[4], acc);
        acc = __builtin_fmaf(pb.y, fcw[5], acc);
        acc = __builtin_fmaf(pb.z, fcw[6], acc);
        acc = __builtin_fmaf(pb.w, fcw[7], acc);
        acc = __builtin_fmaf(pc.x, fcw[8], acc);
        acc = __builtin_fmaf(pc.y, fcw[9], acc);
        const float rc = rcp1p(__builtin_amdgcn_exp2f(acc));
        float y = __builtin_fmaf(rc, fc2w2, fc2wn);           // fc2_w*tanh(acc)
        y += ROR_F(y, 8);
        y += ROR_F(y, 4);
        y += ROR_F(y, 2);
        y += ROR_F(y, 1);                         // whole 16-group holds sum
        if (u == 0) oq[s] = y + fc2bl;
      }
    }
  };

  // ---- pipeline: round r = {A: L0 chunk r, fc chunk r-2 ; B: L1 chunk r-1} ----
#pragma unroll 1
  for (int r = 0; r < NCH + 2; ++r) {
    if (wid == 0) {
      if (r < NCH) a_chunk(r);
      const int m = r - 2;
      if (m >= MFIRST && m < NCH) fc_chunk(m);
    } else {
      if (r >= 1 && r <= NCH) b_chunk(r - 1);
    }
    __syncthreads();
  }
}

extern "C" void kernel_launch(void* const* d_in, const int* in_sizes, int n_in,
                              void* d_out, int out_size, void* d_ws, size_t ws_size,
                              hipStream_t stream) {
  const float* x     = (const float*)d_in[0];
  const float* w_ih0 = (const float*)d_in[1];
  const float* w_hh0 = (const float*)d_in[2];
  const float* b_ih0 = (const float*)d_in[3];
  const float* b_hh0 = (const float*)d_in[4];
  const float* w_ih1 = (const float*)d_in[5];
  const float* w_hh1 = (const float*)d_in[6];
  const float* b_ih1 = (const float*)d_in[7];
  const float* b_hh1 = (const float*)d_in[8];
  const float* fc1_w = (const float*)d_in[9];
  const float* fc1_b = (const float*)d_in[10];
  const float* fc2_w = (const float*)d_in[11];
  const float* fc2_b = (const float*)d_in[12];
  float* out = (float*)d_out;

  lstm_fused<<<dim3(NSEQ / 4), dim3(128), 0, stream>>>(
      x, w_ih0, w_hh0, b_ih0, b_hh0, w_ih1, w_hh1, b_ih1, b_hh1,
      fc1_w, fc1_b, fc2_w, fc2_b, out);
}